// Round 1
// baseline (741.305 us; speedup 1.0000x reference)
//
#include <hip/hip_runtime.h>
#include <hip/hip_bf16.h>
#include <string.h>

#define B_ 256
#define L_ 512
#define H_ 768
#define K_ 64

typedef float  float4v  __attribute__((ext_vector_type(4)));
typedef short  short8v  __attribute__((ext_vector_type(8)));

union BFragU { uint4 u4; short8v s8; };

__device__ inline unsigned short f2bf_bits(float f) {
    union { float f; unsigned int u; } c; c.f = f;
    unsigned int u = c.u;
    u += 0x7fffu + ((u >> 16) & 1u);   // round-to-nearest-even
    return (unsigned short)(u >> 16);
}

// ---------------------------------------------------------------------------
// Kernel 1: emit[131072][64] = features[131072][768] @ W[768][64] + b  (fp32 out)
// bf16 MFMA 16x16x32. W^T staged in LDS (bf16, two H-halves), A direct from
// global (2x dwordx4 per lane per k-step), no barriers inside the K-loop.
// ---------------------------------------------------------------------------
#define WT_STRIDE 408   // 384 + 24 pad ushorts; stride dwords % 32 == 12 -> <=4-way aliasing

__global__ __launch_bounds__(256, 2)
void emit_gemm(const float* __restrict__ A, const float* __restrict__ W,
               const float* __restrict__ bias, float* __restrict__ emit) {
    __shared__ __align__(16) unsigned short Wt[64 * WT_STRIDE];
    const int tid  = threadIdx.x;
    const int lane = tid & 63;
    const int wid  = tid >> 6;
    const int lm   = lane & 15;   // m (A) / n (B) / col (C)
    const int lq   = lane >> 4;   // k-group

    float4v acc[4][4];
    #pragma unroll
    for (int c = 0; c < 4; ++c)
        #pragma unroll
        for (int nt = 0; nt < 4; ++nt)
            acc[c][nt] = (float4v)0.f;

    for (int half = 0; half < 2; ++half) {
        __syncthreads();
        // stage Wt[k][h_local] = bf16(W[half*384 + h_local][k])  (coalesced reads)
        for (int i = tid; i < 384 * 64; i += 256) {
            int h = i >> 6, k = i & 63;
            Wt[k * WT_STRIDE + h] = f2bf_bits(W[(half * 384 + h) * 64 + k]);
        }
        __syncthreads();

        #pragma unroll 2
        for (int ks = 0; ks < 12; ++ks) {
            short8v bfrag[4];
            #pragma unroll
            for (int nt = 0; nt < 4; ++nt) {
                const unsigned short* p =
                    &Wt[(lm + nt * 16) * WT_STRIDE + ks * 32 + lq * 8];
                BFragU bb; bb.u4 = *reinterpret_cast<const uint4*>(p);
                bfrag[nt] = bb.s8;
            }
            #pragma unroll
            for (int c = 0; c < 4; ++c) {
                int row = (blockIdx.x * 4 + c) * 64 + wid * 16 + lm;
                const float* ap = A + (size_t)row * H_ + half * 384 + ks * 32 + lq * 8;
                float4 a0 = *reinterpret_cast<const float4*>(ap);
                float4 a1 = *reinterpret_cast<const float4*>(ap + 4);
                __hip_bfloat162 tt[4];
                tt[0] = __float22bfloat162_rn(make_float2(a0.x, a0.y));
                tt[1] = __float22bfloat162_rn(make_float2(a0.z, a0.w));
                tt[2] = __float22bfloat162_rn(make_float2(a1.x, a1.y));
                tt[3] = __float22bfloat162_rn(make_float2(a1.z, a1.w));
                short8v afrag;
                memcpy(&afrag, tt, 16);
                #pragma unroll
                for (int nt = 0; nt < 4; ++nt)
                    acc[c][nt] = __builtin_amdgcn_mfma_f32_16x16x32_bf16(
                        afrag, bfrag[nt], acc[c][nt], 0, 0, 0);
            }
        }
    }

    // epilogue: C/D map col=lane&15, row=(lane>>4)*4+r  [m89-verified]
    float bv[4];
    #pragma unroll
    for (int nt = 0; nt < 4; ++nt) bv[nt] = bias[nt * 16 + lm];
    #pragma unroll
    for (int c = 0; c < 4; ++c) {
        int rowb = (blockIdx.x * 4 + c) * 64 + wid * 16 + lq * 4;
        #pragma unroll
        for (int nt = 0; nt < 4; ++nt) {
            int col = nt * 16 + lm;
            #pragma unroll
            for (int r = 0; r < 4; ++r)
                emit[(size_t)(rowb + r) * 64 + col] = acc[c][nt][r] + bv[nt];
        }
    }
}

// ---------------------------------------------------------------------------
// Kernel 2: per-batch CRF forward scan + gold score. One wave per chain.
// d_new[k] = m + e[k] + log( sum_i exp(d[i]-m) * expT[i][k] ),
// expT columns in 64 VGPRs, p broadcast through LDS float4 reads.
// ---------------------------------------------------------------------------
__global__ __launch_bounds__(64, 1)
void crf_scan(const float* __restrict__ emit, const float* __restrict__ T,
              const int* __restrict__ tags, const int* __restrict__ mask,
              float* __restrict__ out) {
    const int b    = blockIdx.x;
    const int lane = threadIdx.x;
    __shared__ __align__(16) float pbuf[2][64];

    // sequence length (mask is prefix-true)
    int len = 0;
    #pragma unroll
    for (int j = 0; j < 8; ++j) len += (mask[b * L_ + j * 64 + lane] != 0);
    #pragma unroll
    for (int off = 32; off > 0; off >>= 1) len += __shfl_xor(len, off, 64);

    // expT columns: et[i] = exp(T[i][lane])   (i = "from", lane = "to")
    float et[64];
    #pragma unroll
    for (int i = 0; i < 64; ++i) et[i] = __expf(T[i * 64 + lane]);

    const float* eb = emit + (size_t)b * L_ * 64;

    // gold-path score, lane-parallel over t
    float sc = 0.f;
    for (int t = lane; t < len; t += 64) {
        int tg = tags[b * L_ + t];
        sc += eb[(size_t)t * 64 + tg];
        if (t > 0) sc += T[tags[b * L_ + t - 1] * 64 + tg];
    }
    #pragma unroll
    for (int off = 32; off > 0; off >>= 1) sc += __shfl_xor(sc, off, 64);

    // sequential forward scan
    float d = eb[lane];
    for (int t = 1; t < len; ++t) {
        float e = eb[(size_t)t * 64 + lane];
        float m = __int_as_float(__builtin_amdgcn_readfirstlane(__float_as_int(d)));
        float p = __expf(d - m);
        float* pb = pbuf[t & 1];
        pb[lane] = p;
        const float4* pb4 = reinterpret_cast<const float4*>(pb);
        float a0 = 0.f, a1 = 0.f, a2 = 0.f, a3 = 0.f;
        #pragma unroll
        for (int i = 0; i < 16; ++i) {
            float4 pv = pb4[i];   // broadcast read
            a0 += pv.x * et[i * 4 + 0];
            a1 += pv.y * et[i * 4 + 1];
            a2 += pv.z * et[i * 4 + 2];
            a3 += pv.w * et[i * 4 + 3];
        }
        float s = (a0 + a1) + (a2 + a3);
        d = m + e + __logf(s);
    }

    // log_z = logsumexp(d), full max for the final reduce
    float mx = d;
    #pragma unroll
    for (int off = 32; off > 0; off >>= 1) mx = fmaxf(mx, __shfl_xor(mx, off, 64));
    float z = __expf(d - mx);
    #pragma unroll
    for (int off = 32; off > 0; off >>= 1) z += __shfl_xor(z, off, 64);
    if (lane == 0) out[b] = mx + __logf(z) - sc;
}

extern "C" void kernel_launch(void* const* d_in, const int* in_sizes, int n_in,
                              void* d_out, int out_size, void* d_ws, size_t ws_size,
                              hipStream_t stream) {
    const float* feat = (const float*)d_in[0];
    const float* W    = (const float*)d_in[1];
    const float* bias = (const float*)d_in[2];
    const float* T    = (const float*)d_in[3];
    const int*   tags = (const int*)d_in[4];
    const int*   mask = (const int*)d_in[5];
    float* out  = (float*)d_out;
    float* emit = (float*)d_ws;   // 131072*64 fp32 = 33.5 MB

    hipLaunchKernelGGL(emit_gemm, dim3(512), dim3(256), 0, stream, feat, W, bias, emit);
    hipLaunchKernelGGL(crf_scan,  dim3(B_),  dim3(64),  0, stream, emit, T, tags, mask, out);
}